// Round 9
// baseline (12716.413 us; speedup 1.0000x reference)
//
#include <hip/hip_runtime.h>

typedef _Float16 half8 __attribute__((ext_vector_type(8)));
typedef float floatx4 __attribute__((ext_vector_type(4)));

constexpr int Bn = 16, Cn = 256, Hn = 64, Wn = 96;
constexpr int HW = Hn * Wn;          // 6144
constexpr int Dn = 21, ND = Dn * Dn; // 441
// padded f2 spatial dims (pad=20 each side)
constexpr int PH = Hn + 40;          // 104
constexpr int PW = Wn + 40;          // 136
constexpr int PHW = PH * PW;         // 14144
// pass-2 tile
constexpr int TY = 8, TX = 16;
constexpr int NTY = Hn / TY;         // 8
constexpr int NTX = Wn / TX;         // 6
constexpr int NJ = (TX + 40) / 2;    // 28 window cols per parity
constexpr int GP2 = 253;             // G pitch (f16)
// LDS: G 2*32*253*2 = 32,384 B + B rings 4 waves*2 bufs*2KB = 16,384 B -> 48,768 B -> 3 wg/CU

constexpr size_t F1T_BYTES = (size_t)Bn * HW * Cn * 2;   // 50,331,648
constexpr size_t F2T_BYTES = (size_t)Bn * PHW * Cn * 2;  // 115,867,648
constexpr size_t WS_NEEDED = F1T_BYTES + F2T_BYTES;

constexpr int F1_BLKS = Bn * (HW / 64);    // 1536
constexpr int F2_BLKS = Bn * (PHW / 64);   // 3536

// ---------------- pass 1 (merged): f32 BCHW -> f16 pixel-major ------------
__global__ __launch_bounds__(256)
void tconv_all(const float* __restrict__ f1, const float* __restrict__ f2,
               _Float16* __restrict__ f1t, _Float16* __restrict__ f2t) {
  int blk = blockIdx.x;
  const int t = threadIdx.x;
  const int pxl = t >> 2;            // 0..63
  const int g = t & 3;
  if (blk < F1_BLKS) {
    const int b = blk / (HW / 64);
    const int px = (blk % (HW / 64)) * 64 + pxl;
    const float* src = f1 + (size_t)b * Cn * HW + px;
    _Float16* dst = f1t + ((size_t)b * HW + px) * Cn;
#pragma unroll
    for (int it = 0; it < 8; ++it) {
      const int c0 = (g + it * 4) * 8;
      half8 v;
#pragma unroll
      for (int k = 0; k < 8; ++k)
        v[k] = (_Float16)src[(size_t)(c0 + k) * HW];
      *(half8*)(dst + c0) = v;
    }
  } else {
    blk -= F1_BLKS;
    const int b = blk / (PHW / 64);
    const int ppx = (blk % (PHW / 64)) * 64 + pxl;
    const int y = ppx / PW;
    const int x = ppx - y * PW;
    const int yy = y - 20, xx = x - 20;
    const bool valid = (yy >= 0) & (yy < Hn) & (xx >= 0) & (xx < Wn);
    const float* src = f2 + (size_t)b * Cn * HW + (valid ? (yy * Wn + xx) : 0);
    _Float16* dst = f2t + ((size_t)b * PHW + ppx) * Cn;
#pragma unroll
    for (int it = 0; it < 8; ++it) {
      const int c0 = (g + it * 4) * 8;
      half8 v;
#pragma unroll
      for (int k = 0; k < 8; ++k) {
        const float f = src[(size_t)(c0 + k) * HW];
        v[k] = (_Float16)(valid ? f : 0.0f);
      }
      *(half8*)(dst + c0) = v;
    }
  }
}

// global->LDS DMA. ldsoff MUST be a readfirstlane'd (provably wave-uniform)
// integer: round 8 passed &Bsh[wave][..] directly and the compiler emitted a
// 64-iteration waterfall loop per DMA (63% VALUBusy, 1.7GB scratch spill).
#define GLLDS(gp, ldsoff) \
  __builtin_amdgcn_global_load_lds( \
      (const __attribute__((address_space(1))) void*)(gp), \
      (__attribute__((address_space(3))) void*)(uintptr_t)(ldsoff), 16, 0, 0)
// counted waits; memory clobber orders DMAs/LDS ops, sched_barrier pins MFMAs
#define WAITVM2() do { asm volatile("s_waitcnt vmcnt(2)" ::: "memory"); \
  __builtin_amdgcn_sched_barrier(0); } while (0)
#define WAITVM0() do { asm volatile("s_waitcnt vmcnt(0)" ::: "memory"); \
  __builtin_amdgcn_sched_barrier(0); } while (0)
// asm ds_read: opaque to the LDS-DMA alias tracker (a C++ read here would
// make the waitcnt pass insert a conservative vmcnt(0) and kill the pipeline)
#define DSREAD(dst, addr, OFFSTR) \
  asm volatile("ds_read_b128 %0, %1 offset:" OFFSTR : "=v"(dst) : "v"(addr));

// ---------------- pass 2: correlation via MFMA ----------------------------
// One wg = (b, qa, 8x16 tile, dy-chunk of ~5), BOTH x-parity classes.
// A register-resident (64 VGPR, settled+pinned). B staged wave-privately via
// global_load_lds in a 2-stage ring (2 DMAs/stage in flight under vmcnt(2)),
// consumed with asm ds_read_b128. No barriers in the main loop.
__global__ __launch_bounds__(256, 3)
void corr4(const _Float16* __restrict__ f1t, const _Float16* __restrict__ f2t,
           float* __restrict__ out) {
  __shared__ _Float16 G[2][32][GP2];      // 32,384 B
  __shared__ _Float16 Bsh[4][2][1024];    // 16,384 B (per wave: 2 bufs x 2KB)

  // bijective XCD swizzle: 6144 wgs = 8 XCDs x 768 contiguous
  int bid = (int)blockIdx.x;
  bid = (bid & 7) * 768 + (bid >> 3);
  const int tx = bid % NTX;
  int tmp = bid / NTX;
  const int ty = tmp % NTY;
  tmp /= NTY;
  const int qa = tmp & 1;
  tmp >>= 1;
  const int chunk = tmp & 3;
  const int b = tmp >> 2;
  const int y0 = ty * TY, x0 = tx * TX;

  const int dyLo = chunk * 5;               // 0,5,10,15
  const int r = (chunk == 3) ? 6 : 5;       // dy count in chunk
  const int rows = r + 3;                   // window rows needed
  const int NNc = rows * NJ;                // 224 / 252
  const int ntiles = (NNc + 15) >> 4;       // 14 / 16
  const int ndch = r * Dn;                  // 105 / 126

  const int t = threadIdx.x;
  const int lane = t & 63;
  const int wave = t >> 6;
  const int l15 = lane & 15;
  const int lk = lane >> 4;

  const _Float16* f1b = f1t + (size_t)b * HW * Cn;
  const _Float16* f2b = f2t + (size_t)b * PHW * Cn;
  const float invc = 1.0f / 256.0f;

  // wave-private LDS ring base: PROVABLY uniform via readfirstlane
  const unsigned lbase = __builtin_amdgcn_readfirstlane(
      (unsigned)(uintptr_t)(__attribute__((address_space(3))) void*)&Bsh[wave][0][0]);
  const unsigned lkoff = lk * 256 + l15 * 16;

  const int nw = (ntiles - wave + 3) >> 2;  // tiles for this wave (>=3)
  const int S = 4 * nw;                     // stages (tile x k-quarter)

  for (int qb = 0; qb < 2; ++qb) {
    // ---- A fragments for both m-tiles: load, settle, pin (64 VGPR)
    half8 a0[8], a1[8];
    {
      const int m1 = 16 + l15;
      const _Float16* ap0 = f1b + (size_t)((y0 + qa + 2 * (l15 >> 3)) * Wn + x0 + qb + 2 * (l15 & 7)) * Cn + lk * 8;
      const _Float16* ap1 = f1b + (size_t)((y0 + qa + 2 * (m1 >> 3)) * Wn + x0 + qb + 2 * (m1 & 7)) * Cn + lk * 8;
#pragma unroll
      for (int ks = 0; ks < 8; ++ks) {
        a0[ks] = *(const half8*)(ap0 + ks * 32);
        a1[ks] = *(const half8*)(ap1 + ks * 32);
      }
    }
    asm volatile("s_waitcnt vmcnt(0)" ::: "memory");  // A settled before pipeline
#pragma unroll
    for (int ks = 0; ks < 8; ++ks)
      asm volatile("" : "+v"(a0[ks]), "+v"(a1[ks]));

    // per-lane global base (bytes) for tile tt: n = (wave+4*tt)*16 + l15
    auto gsrc = [&](int tt) -> const char* {
      int n = (wave + 4 * tt) * 16 + l15;
      if (n >= NNc) n = 0;                  // clamp: dup load, deposit guarded
      const unsigned i = (unsigned)n / (unsigned)NJ;
      const unsigned j = (unsigned)n % (unsigned)NJ;
      const size_t elem = ((size_t)((y0 + qa + 2 * ((int)i + dyLo)) * PW
                                    + (x0 + qb + 2 * (int)j))) * Cn + lk * 8;
      return (const char*)(f2b + elem);
    };
    // stage = (tile, quarter q): 2 DMAs -> 1024B each (64 lanes x 16B)
    auto issue2 = [&](unsigned loff, const char* g) {
      GLLDS(g, loff);
      GLLDS(g + 64, loff + 1024);
    };

    // prologue: stages 0 (tile0,q0 -> buf0) and 1 (tile0,q1 -> buf1)
    const char* gp_cur = gsrc(0);
    const char* gp_nxt = (nw > 1) ? gsrc(1) : gp_cur;
    issue2(lbase, gp_cur);
    issue2(lbase + 2048, gp_cur + 128);

    floatx4 acc0 = {0.f, 0.f, 0.f, 0.f};
    floatx4 acc1 = {0.f, 0.f, 0.f, 0.f};
    int tt = 0;
    for (int s = 0; s < S; ++s) {
      const int q = s & 3;
      if (s + 1 < S) { WAITVM2(); } else { WAITVM0(); }  // this stage's DMAs done

      // B fragments from this stage's buffer, then 4 MFMAs (K=64 slice)
      half8 bf0, bf1;
      const unsigned baddr = lbase + (unsigned)((q & 1) * 2048) + lkoff;
      DSREAD(bf0, baddr, "0")
      DSREAD(bf1, baddr, "1024")
      asm volatile("s_waitcnt lgkmcnt(0)");
      __builtin_amdgcn_sched_barrier(0);
#pragma unroll
      for (int ks = 0; ks < 8; ++ks)
        asm volatile("" : "+v"(a0[ks]), "+v"(a1[ks]));
      const int ks0 = 2 * q;
      acc0 = __builtin_amdgcn_mfma_f32_16x16x32_f16(a0[ks0], bf0, acc0, 0, 0, 0);
      acc1 = __builtin_amdgcn_mfma_f32_16x16x32_f16(a1[ks0], bf0, acc1, 0, 0, 0);
      acc0 = __builtin_amdgcn_mfma_f32_16x16x32_f16(a0[ks0 + 1], bf1, acc0, 0, 0, 0);
      acc1 = __builtin_amdgcn_mfma_f32_16x16x32_f16(a1[ks0 + 1], bf1, acc1, 0, 0, 0);

      // issue stage s+2 into the buffer just consumed
      const int s2 = s + 2;
      if (s2 < S) {
        const int q2 = (q + 2) & 3;
        const char* g2 = (q < 2) ? gp_cur : gp_nxt;
        issue2(lbase + (unsigned)((q & 1) * 2048), g2 + q2 * 128);
      }

      if (q == 3) {
        // tile done: deposit G (pre-scaled) and rotate tile pointers
        const int n = (wave + 4 * tt) * 16 + l15;
        if (n < NNc) {
#pragma unroll
          for (int rr = 0; rr < 4; ++rr) {
            G[qb][4 * lk + rr][n]      = (_Float16)(acc0[rr] * invc);
            G[qb][16 + 4 * lk + rr][n] = (_Float16)(acc1[rr] * invc);
          }
        }
        acc0 = {0.f, 0.f, 0.f, 0.f};
        acc1 = {0.f, 0.f, 0.f, 0.f};
        ++tt;
        gp_cur = gp_nxt;
        gp_nxt = (tt + 1 < nw) ? gsrc(tt + 1) : gp_cur;
      }
    }
  }
  __syncthreads();

  // merged epilogue: ndch channels (dy in [dyLo, dyLo+r)), full 64B lines.
  // thread t -> (d-sub = t>>4, alpha = (t>>2)&3, x-quad = t&3)
  {
    const int niter = (ndch + 15) >> 4;
    const int dsub = t >> 4;
    const int alpha = (t >> 2) & 3;
    const int xq = t & 3;
    const int yy = y0 + qa + 2 * alpha;
    float* ob = out + (size_t)b * ND * HW + yy * Wn + x0 + xq * 4;
    const int m0 = alpha * 8 + xq * 2;
    for (int q = 0; q < niter; ++q) {
      const int dch = q * 16 + dsub;
      if (dch < ndch) {
        const unsigned dyl = (unsigned)dch / 21u;
        const int dx = dch - (int)dyl * 21;
        const int dy = dyLo + (int)dyl;
        const int col = ((int)dyl + alpha) * NJ + xq * 2 + dx;  // irel = alpha+dy-dyLo
        floatx4 v;
        v[0] = (float)G[0][m0][col];
        v[1] = (float)G[1][m0][col];
        v[2] = (float)G[0][m0 + 1][col + 1];
        v[3] = (float)G[1][m0 + 1][col + 1];
        __builtin_nontemporal_store(v, (floatx4*)(ob + (size_t)(dy * Dn + dx) * HW));
      }
    }
  }
}

// ---------------- fallback (round-1 kernel) if ws too small ---------------
constexpr int FTY = 8, FTX = 8;
constexpr int FNTY = Hn / FTY, FNTX = Wn / FTX;
constexpr int FNJ = 24, FNTILES = 36, FGP = 580;

__global__ __launch_bounds__(256, 4)
void corr_fallback(const float* __restrict__ f1, const float* __restrict__ f2,
                   float* __restrict__ out) {
  __shared__ float G[16 * FGP];
  const int bid = blockIdx.x;
  const int cls = bid & 3;
  const int t2 = bid >> 2;
  const int tx = t2 % FNTX;
  const int t3 = t2 / FNTX;
  const int ty = t3 % FNTY;
  const int b = t3 / FNTY;
  const int qa = cls >> 1, qb = cls & 1;
  const int y0 = ty * FTY, x0 = tx * FTX;
  const int lane = threadIdx.x & 63;
  const int wave = threadIdx.x >> 6;
  const int l15 = lane & 15;
  const int lk = lane >> 4;
  const float* f1b = f1 + b * (Cn * HW);
  const float* f2b = f2 + b * (Cn * HW);
  const int ay = y0 + qa + 2 * (l15 >> 2);
  const int ax = x0 + qb + 2 * (l15 & 3);
  const float* f1p = f1b + ay * Wn + ax;
  half8 afrag[8];
#pragma unroll
  for (int ks = 0; ks < 8; ++ks)
#pragma unroll
    for (int tt = 0; tt < 8; ++tt)
      afrag[ks][tt] = (_Float16)f1p[(ks * 32 + lk * 8 + tt) * HW];
  const int nt0 = wave * (FNTILES / 4);
  for (int nt = nt0; nt < nt0 + FNTILES / 4; ++nt) {
    const unsigned n = nt * 16 + l15;
    const int i = n / (unsigned)FNJ;
    const int j = n % (unsigned)FNJ;
    const int y2 = y0 - 20 + qa + 2 * i;
    const int x2 = x0 - 20 + qb + 2 * j;
    const bool inb = (y2 >= 0) & (y2 < Hn) & (x2 >= 0) & (x2 < Wn);
    const float* f2p = f2b + (inb ? (y2 * Wn + x2) : 0);
    floatx4 acc = {0.f, 0.f, 0.f, 0.f};
#pragma unroll
    for (int ks = 0; ks < 8; ++ks) {
      half8 bfrag;
#pragma unroll
      for (int tt = 0; tt < 8; ++tt) {
        const float v = f2p[(ks * 32 + lk * 8 + tt) * HW];
        bfrag[tt] = (_Float16)(inb ? v : 0.0f);
      }
      acc = __builtin_amdgcn_mfma_f32_16x16x32_f16(afrag[ks], bfrag, acc, 0, 0, 0);
    }
#pragma unroll
    for (int r = 0; r < 4; ++r)
      G[(4 * lk + r) * FGP + n] = acc[r];
  }
  __syncthreads();
  float* outb = out + b * (ND * HW);
  const float invc = 1.0f / 256.0f;
  for (int o = threadIdx.x; o < ND * 16; o += 256) {
    const int d = o >> 4;
    const int m = o & 15;
    const int dy = (unsigned)d / 21u;
    const int dx = (unsigned)d % 21u;
    const int alpha = m >> 2, beta = m & 3;
    const float val = G[m * FGP + (alpha + dy) * FNJ + (beta + dx)] * invc;
    outb[d * HW + (y0 + qa + 2 * alpha) * Wn + (x0 + qb + 2 * beta)] = val;
  }
}

extern "C" void kernel_launch(void* const* d_in, const int* in_sizes, int n_in,
                              void* d_out, int out_size, void* d_ws, size_t ws_size,
                              hipStream_t stream) {
  const float* f1 = (const float*)d_in[0];
  const float* f2 = (const float*)d_in[1];
  float* out = (float*)d_out;
  if (ws_size >= WS_NEEDED) {
    _Float16* f1t = (_Float16*)d_ws;
    _Float16* f2t = (_Float16*)((char*)d_ws + F1T_BYTES);
    tconv_all<<<dim3(F1_BLKS + F2_BLKS), dim3(256), 0, stream>>>(f1, f2, f1t, f2t);
    corr4<<<dim3(Bn * 2 * NTY * NTX * 4), dim3(256), 0, stream>>>(f1t, f2t, out);
  } else {
    corr_fallback<<<dim3(Bn * FNTY * FNTX * 4), dim3(256), 0, stream>>>(f1, f2, out);
  }
}

// Round 10
// 339.532 us; speedup vs baseline: 37.4528x; 37.4528x over previous
//
#include <hip/hip_runtime.h>

typedef _Float16 half8 __attribute__((ext_vector_type(8)));
typedef float floatx4 __attribute__((ext_vector_type(4)));

constexpr int Bn = 16, Cn = 256, Hn = 64, Wn = 96;
constexpr int HW = Hn * Wn;          // 6144
constexpr int Dn = 21, ND = Dn * Dn; // 441
// padded f2 spatial dims (pad=20 each side)
constexpr int PH = Hn + 40;          // 104
constexpr int PW = Wn + 40;          // 136
constexpr int PHW = PH * PW;         // 14144
// pass-2 tile
constexpr int TY = 8, TX = 16;
constexpr int NTY = Hn / TY;         // 8
constexpr int NTX = Wn / TX;         // 6
constexpr int NJ = (TX + 40) / 2;    // 28 window cols per parity
constexpr int GP5 = 260;             // G pitch f16: row stride 520B -> 16 deposit rows hit distinct banks
// LDS: 2 parities x 32 rows x 260 f16 = 33,280 B -> 4 wg/CU (16 waves)

constexpr size_t F1T_BYTES = (size_t)Bn * HW * Cn * 2;   // 50,331,648
constexpr size_t F2T_BYTES = (size_t)Bn * PHW * Cn * 2;  // 115,867,648
constexpr size_t WS_NEEDED = F1T_BYTES + F2T_BYTES;

constexpr int F1_BLKS = Bn * (HW / 64);    // 1536
constexpr int F2_BLKS = Bn * (PHW / 64);   // 3536

// ---------------- pass 1 (merged): f32 BCHW -> f16 pixel-major ------------
__global__ __launch_bounds__(256)
void tconv_all(const float* __restrict__ f1, const float* __restrict__ f2,
               _Float16* __restrict__ f1t, _Float16* __restrict__ f2t) {
  int blk = blockIdx.x;
  const int t = threadIdx.x;
  const int pxl = t >> 2;            // 0..63
  const int g = t & 3;
  if (blk < F1_BLKS) {
    const int b = blk / (HW / 64);
    const int px = (blk % (HW / 64)) * 64 + pxl;
    const float* src = f1 + (size_t)b * Cn * HW + px;
    _Float16* dst = f1t + ((size_t)b * HW + px) * Cn;
#pragma unroll
    for (int it = 0; it < 8; ++it) {
      const int c0 = (g + it * 4) * 8;
      half8 v;
#pragma unroll
      for (int k = 0; k < 8; ++k)
        v[k] = (_Float16)src[(size_t)(c0 + k) * HW];
      *(half8*)(dst + c0) = v;
    }
  } else {
    blk -= F1_BLKS;
    const int b = blk / (PHW / 64);
    const int ppx = (blk % (PHW / 64)) * 64 + pxl;
    const int y = ppx / PW;
    const int x = ppx - y * PW;
    const int yy = y - 20, xx = x - 20;
    const bool valid = (yy >= 0) & (yy < Hn) & (xx >= 0) & (xx < Wn);
    const float* src = f2 + (size_t)b * Cn * HW + (valid ? (yy * Wn + xx) : 0);
    _Float16* dst = f2t + ((size_t)b * PHW + ppx) * Cn;
#pragma unroll
    for (int it = 0; it < 8; ++it) {
      const int c0 = (g + it * 4) * 8;
      half8 v;
#pragma unroll
      for (int k = 0; k < 8; ++k) {
        const float f = src[(size_t)(c0 + k) * HW];
        v[k] = (_Float16)(valid ? f : 0.0f);
      }
      *(half8*)(dst + c0) = v;
    }
  }
}

// ---------------- pass 2: correlation via MFMA ----------------------------
// One wg = (b, qa, 8x16 tile, dy-chunk), BOTH x-parity classes.
// Round-4 structure (plain loads, VGPR~68 -- fastest verified) with LDS cut
// to 33.3KB so 4 wg/CU are resident: the loop is latency-bound (rounds 4-9),
// so time scales ~1/waves; TLP is the compiler-proof lever.
__global__ __launch_bounds__(256, 4)
void corr5(const _Float16* __restrict__ f1t, const _Float16* __restrict__ f2t,
           float* __restrict__ out) {
  __shared__ _Float16 G[2][32][GP5];  // 33,280 B -> 4 wg/CU

  // bijective XCD swizzle: 6144 wgs = 8 XCDs x 768 contiguous
  int bid = (int)blockIdx.x;
  bid = (bid & 7) * 768 + (bid >> 3);
  const int tx = bid % NTX;
  int tmp = bid / NTX;
  const int ty = tmp % NTY;
  tmp /= NTY;
  const int qa = tmp & 1;
  tmp >>= 1;
  const int chunk = tmp & 3;
  const int b = tmp >> 2;
  const int y0 = ty * TY, x0 = tx * TX;

  // dy chunks: (6,5,5,5) -> dyLo 0,6,11,16; staged window rows = r+3
  const int r = (chunk == 0) ? 6 : 5;
  const int dyLo = (chunk == 0) ? 0 : (1 + 5 * chunk);  // 0,6,11,16
  const int rows = r + 3;                   // 9 / 8
  const int NNc = rows * NJ;                // 252 / 224
  const int ntiles = (NNc + 15) >> 4;       // 16 / 14
  const int ndch = r * Dn;                  // 126 / 105

  const int t = threadIdx.x;
  const int lane = t & 63;
  const int wave = t >> 6;
  const int l15 = lane & 15;
  const int lk = lane >> 4;

  const _Float16* f1b = f1t + (size_t)b * HW * Cn;
  const _Float16* f2b = f2t + (size_t)b * PHW * Cn;
  const float invc = 1.0f / 256.0f;

  for (int qb = 0; qb < 2; ++qb) {
    // A fragments for both m-tiles (compiler keeps ~afrag working set small;
    // accepted: rounds 4-9 proved forcing residency backfires)
    half8 afrag[2][8];
#pragma unroll
    for (int mt = 0; mt < 2; ++mt) {
      const int m = mt * 16 + l15;
      const int ay = y0 + qa + 2 * (m >> 3);
      const int ax = x0 + qb + 2 * (m & 7);
      const _Float16* ap = f1b + (size_t)(ay * Wn + ax) * Cn + lk * 8;
#pragma unroll
      for (int ks = 0; ks < 8; ++ks)
        afrag[mt][ks] = *(const half8*)(ap + ks * 32);
    }

    for (int nt = wave; nt < ntiles; nt += 4) {
      const int n = nt * 16 + l15;
      const bool nvalid = n < NNc;
      const int nc = nvalid ? n : 0;
      const int i = nc / NJ;                // i_rel in [0,rows)
      const int j = nc % NJ;
      const int py = y0 + qa + 2 * (i + dyLo);   // padded row
      const int px = x0 + qb + 2 * j;
      const _Float16* bp = f2b + (size_t)(py * PW + px) * Cn + lk * 8;
      half8 bfrag[8];
#pragma unroll
      for (int ks = 0; ks < 8; ++ks)
        bfrag[ks] = *(const half8*)(bp + ks * 32);

      floatx4 acc0 = {0.f, 0.f, 0.f, 0.f};
      floatx4 acc1 = {0.f, 0.f, 0.f, 0.f};
#pragma unroll
      for (int ks = 0; ks < 8; ++ks) {
        acc0 = __builtin_amdgcn_mfma_f32_16x16x32_f16(afrag[0][ks], bfrag[ks], acc0, 0, 0, 0);
        acc1 = __builtin_amdgcn_mfma_f32_16x16x32_f16(afrag[1][ks], bfrag[ks], acc1, 0, 0, 0);
      }
      if (nvalid) {
#pragma unroll
        for (int rr = 0; rr < 4; ++rr) {
          G[qb][4 * lk + rr][n]      = (_Float16)(acc0[rr] * invc);
          G[qb][16 + 4 * lk + rr][n] = (_Float16)(acc1[rr] * invc);
        }
      }
    }
  }
  __syncthreads();

  // merged epilogue: ndch channels (dy in [dyLo, dyLo+r)), full 64B lines.
  // thread t -> (d-sub = t>>4, alpha = (t>>2)&3, x-quad = t&3); each lane
  // writes float4 covering x = x0+xq*4 .. +3 -> 4 lanes cover a 64B line.
  {
    const int niter = (ndch + 15) >> 4;     // 8 / 7
    const int dsub = t >> 4;
    const int alpha = (t >> 2) & 3;
    const int xq = t & 3;
    const int yy = y0 + qa + 2 * alpha;
    float* ob = out + (size_t)b * ND * HW + yy * Wn + x0 + xq * 4;
    const int m0 = alpha * 8 + xq * 2;
    for (int q = 0; q < niter; ++q) {
      const int dch = q * 16 + dsub;
      if (dch < ndch) {
        const unsigned dyl = (unsigned)dch / 21u;
        const int dx = dch - (int)dyl * 21;
        const int dy = dyLo + (int)dyl;
        const int col = ((int)dyl + alpha) * NJ + xq * 2 + dx;  // i_rel = alpha+dyl
        floatx4 v;
        v[0] = (float)G[0][m0][col];            // x even, beta=xq*2
        v[1] = (float)G[1][m0][col];            // x odd
        v[2] = (float)G[0][m0 + 1][col + 1];    // beta=xq*2+1
        v[3] = (float)G[1][m0 + 1][col + 1];
        __builtin_nontemporal_store(v, (floatx4*)(ob + (size_t)(dy * Dn + dx) * HW));
      }
    }
  }
}

// ---------------- fallback (round-1 kernel) if ws too small ---------------
constexpr int FTY = 8, FTX = 8;
constexpr int FNTY = Hn / FTY, FNTX = Wn / FTX;
constexpr int FNJ = 24, FNTILES = 36, FGP = 580;

__global__ __launch_bounds__(256, 4)
void corr_fallback(const float* __restrict__ f1, const float* __restrict__ f2,
                   float* __restrict__ out) {
  __shared__ float G[16 * FGP];
  const int bid = blockIdx.x;
  const int cls = bid & 3;
  const int t2 = bid >> 2;
  const int tx = t2 % FNTX;
  const int t3 = t2 / FNTX;
  const int ty = t3 % FNTY;
  const int b = t3 / FNTY;
  const int qa = cls >> 1, qb = cls & 1;
  const int y0 = ty * FTY, x0 = tx * FTX;
  const int lane = threadIdx.x & 63;
  const int wave = threadIdx.x >> 6;
  const int l15 = lane & 15;
  const int lk = lane >> 4;
  const float* f1b = f1 + b * (Cn * HW);
  const float* f2b = f2 + b * (Cn * HW);
  const int ay = y0 + qa + 2 * (l15 >> 2);
  const int ax = x0 + qb + 2 * (l15 & 3);
  const float* f1p = f1b + ay * Wn + ax;
  half8 afrag[8];
#pragma unroll
  for (int ks = 0; ks < 8; ++ks)
#pragma unroll
    for (int tt = 0; tt < 8; ++tt)
      afrag[ks][tt] = (_Float16)f1p[(ks * 32 + lk * 8 + tt) * HW];
  const int nt0 = wave * (FNTILES / 4);
  for (int nt = nt0; nt < nt0 + FNTILES / 4; ++nt) {
    const unsigned n = nt * 16 + l15;
    const int i = n / (unsigned)FNJ;
    const int j = n % (unsigned)FNJ;
    const int y2 = y0 - 20 + qa + 2 * i;
    const int x2 = x0 - 20 + qb + 2 * j;
    const bool inb = (y2 >= 0) & (y2 < Hn) & (x2 >= 0) & (x2 < Wn);
    const float* f2p = f2b + (inb ? (y2 * Wn + x2) : 0);
    floatx4 acc = {0.f, 0.f, 0.f, 0.f};
#pragma unroll
    for (int ks = 0; ks < 8; ++ks) {
      half8 bfrag;
#pragma unroll
      for (int tt = 0; tt < 8; ++tt) {
        const float v = f2p[(ks * 32 + lk * 8 + tt) * HW];
        bfrag[tt] = (_Float16)(inb ? v : 0.0f);
      }
      acc = __builtin_amdgcn_mfma_f32_16x16x32_f16(afrag[ks], bfrag, acc, 0, 0, 0);
    }
#pragma unroll
    for (int r = 0; r < 4; ++r)
      G[(4 * lk + r) * FGP + n] = acc[r];
  }
  __syncthreads();
  float* outb = out + b * (ND * HW);
  const float invc = 1.0f / 256.0f;
  for (int o = threadIdx.x; o < ND * 16; o += 256) {
    const int d = o >> 4;
    const int m = o & 15;
    const int dy = (unsigned)d / 21u;
    const int dx = (unsigned)d % 21u;
    const int alpha = m >> 2, beta = m & 3;
    const float val = G[m * FGP + (alpha + dy) * FNJ + (beta + dx)] * invc;
    outb[d * HW + (y0 + qa + 2 * alpha) * Wn + (x0 + qb + 2 * beta)] = val;
  }
}

extern "C" void kernel_launch(void* const* d_in, const int* in_sizes, int n_in,
                              void* d_out, int out_size, void* d_ws, size_t ws_size,
                              hipStream_t stream) {
  const float* f1 = (const float*)d_in[0];
  const float* f2 = (const float*)d_in[1];
  float* out = (float*)d_out;
  if (ws_size >= WS_NEEDED) {
    _Float16* f1t = (_Float16*)d_ws;
    _Float16* f2t = (_Float16*)((char*)d_ws + F1T_BYTES);
    tconv_all<<<dim3(F1_BLKS + F2_BLKS), dim3(256), 0, stream>>>(f1, f2, f1t, f2t);
    corr5<<<dim3(Bn * 2 * NTY * NTX * 4), dim3(256), 0, stream>>>(f1t, f2t, out);
  } else {
    corr_fallback<<<dim3(Bn * FNTY * FNTX * 4), dim3(256), 0, stream>>>(f1, f2, out);
  }
}

// Round 11
// 287.850 us; speedup vs baseline: 44.1773x; 1.1795x over previous
//
#include <hip/hip_runtime.h>

typedef _Float16 half8 __attribute__((ext_vector_type(8)));
typedef float floatx4 __attribute__((ext_vector_type(4)));

constexpr int Bn = 16, Cn = 256, Hn = 64, Wn = 96;
constexpr int HW = Hn * Wn;          // 6144
constexpr int Dn = 21, ND = Dn * Dn; // 441
// padded f2 spatial dims (pad=20 each side)
constexpr int PH = Hn + 40;          // 104
constexpr int PW = Wn + 40;          // 136
constexpr int PHW = PH * PW;         // 14144
// pass-2 tile
constexpr int TY = 8, TX = 16;
constexpr int NTY = Hn / TY;         // 8
constexpr int NTX = Wn / TX;         // 6
constexpr int NJ = (TX + 40) / 2;    // 28 window cols per parity
constexpr int GPITCH = 396;          // f16 pitch (4-row delta -> disjoint bank octets)
// LDS: 2 parity classes x 32 rows x 396 f16 = 50688 B -> 3 wg/CU

constexpr size_t F1T_BYTES = (size_t)Bn * HW * Cn * 2;   // 50,331,648
constexpr size_t F2T_BYTES = (size_t)Bn * PHW * Cn * 2;  // 115,867,648
constexpr size_t WS_NEEDED = F1T_BYTES + F2T_BYTES;

constexpr int F1_BLKS = Bn * (HW / 64);    // 1536
constexpr int F2_BLKS = Bn * (PHW / 64);   // 3536

// ---------------- pass 1 (merged): f32 BCHW -> f16 pixel-major ------------
__global__ __launch_bounds__(256)
void tconv_all(const float* __restrict__ f1, const float* __restrict__ f2,
               _Float16* __restrict__ f1t, _Float16* __restrict__ f2t) {
  int blk = blockIdx.x;
  const int t = threadIdx.x;
  const int pxl = t >> 2;            // 0..63
  const int g = t & 3;
  if (blk < F1_BLKS) {
    const int b = blk / (HW / 64);
    const int px = (blk % (HW / 64)) * 64 + pxl;
    const float* src = f1 + (size_t)b * Cn * HW + px;
    _Float16* dst = f1t + ((size_t)b * HW + px) * Cn;
#pragma unroll
    for (int it = 0; it < 8; ++it) {
      const int c0 = (g + it * 4) * 8;
      half8 v;
#pragma unroll
      for (int k = 0; k < 8; ++k)
        v[k] = (_Float16)src[(size_t)(c0 + k) * HW];
      *(half8*)(dst + c0) = v;
    }
  } else {
    blk -= F1_BLKS;
    const int b = blk / (PHW / 64);
    const int ppx = (blk % (PHW / 64)) * 64 + pxl;
    const int y = ppx / PW;
    const int x = ppx - y * PW;
    const int yy = y - 20, xx = x - 20;
    const bool valid = (yy >= 0) & (yy < Hn) & (xx >= 0) & (xx < Wn);
    const float* src = f2 + (size_t)b * Cn * HW + (valid ? (yy * Wn + xx) : 0);
    _Float16* dst = f2t + ((size_t)b * PHW + ppx) * Cn;
#pragma unroll
    for (int it = 0; it < 8; ++it) {
      const int c0 = (g + it * 4) * 8;
      half8 v;
#pragma unroll
      for (int k = 0; k < 8; ++k) {
        const float f = src[(size_t)(c0 + k) * HW];
        v[k] = (_Float16)(valid ? f : 0.0f);
      }
      *(half8*)(dst + c0) = v;
    }
  }
}

// ---------------- pass 2: correlation via MFMA ----------------------------
// One wg = (b, qa, 8x16 tile, window-row chunk), BOTH x-parity classes.
// Round-4 verified structure, but the nt loop processes TWO independent
// n-tiles per iteration (nt, nt+4; wave stride 8): two fully independent
// load->MFMA streams so even a register-minimal schedule can overlap one
// stream's loads with the other's compute (rounds 4-10: single stream gets
// serialized into ~8 dependent round-trips per tile).
__global__ __launch_bounds__(256, 3)
void corr6(const _Float16* __restrict__ f1t, const _Float16* __restrict__ f2t,
           float* __restrict__ out) {
  __shared__ _Float16 G[2][32 * GPITCH];  // 50,688 B -> 3 wg/CU

  // bijective XCD swizzle: 3072 wgs = 8 XCDs x 384 contiguous
  int bid = (int)blockIdx.x;
  bid = (bid & 7) * 384 + (bid >> 3);
  const int tx = bid % NTX;
  int tmp = bid / NTX;
  const int ty = tmp % NTY;
  tmp /= NTY;
  const int qa = tmp & 1;
  tmp >>= 1;
  const int chunk = tmp & 1;
  const int b = tmp >> 1;
  const int y0 = ty * TY, x0 = tx * TX;
  const int i0 = chunk ? 11 : 0;        // window row offset
  const int nrows = chunk ? 13 : 14;
  const int NNc = nrows * NJ;           // 364 / 392
  const int ntiles = (NNc + 15) / 16;   // 23 / 25

  const int t = threadIdx.x;
  const int lane = t & 63;
  const int wave = t >> 6;
  const int l15 = lane & 15;
  const int lk = lane >> 4;

  const _Float16* f1b = f1t + (size_t)b * HW * Cn;
  const _Float16* f2b = f2t + (size_t)b * PHW * Cn;
  const float invc = 1.0f / 256.0f;

  for (int qb = 0; qb < 2; ++qb) {
    // A fragments for both m-tiles
    half8 afrag[2][8];
#pragma unroll
    for (int mt = 0; mt < 2; ++mt) {
      const int m = mt * 16 + l15;
      const int ay = y0 + qa + 2 * (m >> 3);
      const int ax = x0 + qb + 2 * (m & 7);
      const _Float16* ap = f1b + (size_t)(ay * Wn + ax) * Cn + lk * 8;
#pragma unroll
      for (int ks = 0; ks < 8; ++ks)
        afrag[mt][ks] = *(const half8*)(ap + ks * 32);
    }

    // paired-tile loop: tiles (nt, nt+4), wave stride 8 covers all residues
    for (int nt = wave; nt < ntiles; nt += 8) {
      const int nA = nt * 16 + l15;
      const bool vA = nA < NNc;
      const int ncA = vA ? nA : 0;
      const int iA = ncA / NJ, jA = ncA % NJ;
      const _Float16* bpA = f2b + (size_t)((y0 + qa + 2 * (iA + i0)) * PW
                                           + (x0 + qb + 2 * jA)) * Cn + lk * 8;
      const int nB = (nt + 4) * 16 + l15;
      const bool vB = nB < NNc;
      const int ncB = vB ? nB : 0;
      const int iB = ncB / NJ, jB = ncB % NJ;
      const _Float16* bpB = f2b + (size_t)((y0 + qa + 2 * (iB + i0)) * PW
                                           + (x0 + qb + 2 * jB)) * Cn + lk * 8;

      // both tiles' loads issued before any MFMA (independent streams)
      half8 bA[8], bB[8];
#pragma unroll
      for (int ks = 0; ks < 8; ++ks) {
        bA[ks] = *(const half8*)(bpA + ks * 32);
        bB[ks] = *(const half8*)(bpB + ks * 32);
      }

      floatx4 accA0 = {0.f, 0.f, 0.f, 0.f};
      floatx4 accA1 = {0.f, 0.f, 0.f, 0.f};
      floatx4 accB0 = {0.f, 0.f, 0.f, 0.f};
      floatx4 accB1 = {0.f, 0.f, 0.f, 0.f};
#pragma unroll
      for (int ks = 0; ks < 8; ++ks) {
        accA0 = __builtin_amdgcn_mfma_f32_16x16x32_f16(afrag[0][ks], bA[ks], accA0, 0, 0, 0);
        accA1 = __builtin_amdgcn_mfma_f32_16x16x32_f16(afrag[1][ks], bA[ks], accA1, 0, 0, 0);
        accB0 = __builtin_amdgcn_mfma_f32_16x16x32_f16(afrag[0][ks], bB[ks], accB0, 0, 0, 0);
        accB1 = __builtin_amdgcn_mfma_f32_16x16x32_f16(afrag[1][ks], bB[ks], accB1, 0, 0, 0);
      }
      if (vA) {
#pragma unroll
        for (int r = 0; r < 4; ++r) {
          G[qb][(4 * lk + r) * GPITCH + nA]      = (_Float16)(accA0[r] * invc);
          G[qb][(16 + 4 * lk + r) * GPITCH + nA] = (_Float16)(accA1[r] * invc);
        }
      }
      if (vB) {
#pragma unroll
        for (int r = 0; r < 4; ++r) {
          G[qb][(4 * lk + r) * GPITCH + nB]      = (_Float16)(accB0[r] * invc);
          G[qb][(16 + 4 * lk + r) * GPITCH + nB] = (_Float16)(accB1[r] * invc);
        }
      }
    }
  }
  __syncthreads();

  // merged epilogue for this chunk's dy range:
  // chunk 0: dy in [0,10] (231 ch); chunk 1: dy in [11,20] (210 ch)
  // thread t -> (d-sub = t>>4, alpha = (t>>2)&3, x-quad = t&3); each lane
  // writes float4 covering x = x0+xq*4 .. +3 -> 4 lanes cover a 64B line.
  {
    const int dyLo = chunk ? 11 : 0;
    const int ndch = chunk ? 210 : 231;
    const int niter = (ndch + 15) / 16;   // 14 / 15
    const int dsub = t >> 4;
    const int alpha = (t >> 2) & 3;
    const int xq = t & 3;
    const int yy = y0 + qa + 2 * alpha;
    float* ob = out + (size_t)b * ND * HW + yy * Wn + x0 + xq * 4;
    const int m0 = alpha * 8 + xq * 2;
    for (int q = 0; q < niter; ++q) {
      const int dch = q * 16 + dsub;
      if (dch < ndch) {
        const unsigned dyl = (unsigned)dch / 21u;
        const int dx = dch - (int)dyl * 21;
        const int dy = dyLo + (int)dyl;
        const int col = (alpha + dy - i0) * NJ + xq * 2 + dx;
        floatx4 v;
        v[0] = (float)G[0][m0 * GPITCH + col];            // x even, beta=xq*2
        v[1] = (float)G[1][m0 * GPITCH + col];            // x odd
        v[2] = (float)G[0][(m0 + 1) * GPITCH + col + 1];  // beta=xq*2+1
        v[3] = (float)G[1][(m0 + 1) * GPITCH + col + 1];
        __builtin_nontemporal_store(v, (floatx4*)(ob + (size_t)(dy * Dn + dx) * HW));
      }
    }
  }
}

// ---------------- fallback (round-1 kernel) if ws too small ---------------
constexpr int FTY = 8, FTX = 8;
constexpr int FNTY = Hn / FTY, FNTX = Wn / FTX;
constexpr int FNJ = 24, FNTILES = 36, FGP = 580;

__global__ __launch_bounds__(256, 4)
void corr_fallback(const float* __restrict__ f1, const float* __restrict__ f2,
                   float* __restrict__ out) {
  __shared__ float G[16 * FGP];
  const int bid = blockIdx.x;
  const int cls = bid & 3;
  const int t2 = bid >> 2;
  const int tx = t2 % FNTX;
  const int t3 = t2 / FNTX;
  const int ty = t3 % FNTY;
  const int b = t3 / FNTY;
  const int qa = cls >> 1, qb = cls & 1;
  const int y0 = ty * FTY, x0 = tx * FTX;
  const int lane = threadIdx.x & 63;
  const int wave = threadIdx.x >> 6;
  const int l15 = lane & 15;
  const int lk = lane >> 4;
  const float* f1b = f1 + b * (Cn * HW);
  const float* f2b = f2 + b * (Cn * HW);
  const int ay = y0 + qa + 2 * (l15 >> 2);
  const int ax = x0 + qb + 2 * (l15 & 3);
  const float* f1p = f1b + ay * Wn + ax;
  half8 afrag[8];
#pragma unroll
  for (int ks = 0; ks < 8; ++ks)
#pragma unroll
    for (int tt = 0; tt < 8; ++tt)
      afrag[ks][tt] = (_Float16)f1p[(ks * 32 + lk * 8 + tt) * HW];
  const int nt0 = wave * (FNTILES / 4);
  for (int nt = nt0; nt < nt0 + FNTILES / 4; ++nt) {
    const unsigned n = nt * 16 + l15;
    const int i = n / (unsigned)FNJ;
    const int j = n % (unsigned)FNJ;
    const int y2 = y0 - 20 + qa + 2 * i;
    const int x2 = x0 - 20 + qb + 2 * j;
    const bool inb = (y2 >= 0) & (y2 < Hn) & (x2 >= 0) & (x2 < Wn);
    const float* f2p = f2b + (inb ? (y2 * Wn + x2) : 0);
    floatx4 acc = {0.f, 0.f, 0.f, 0.f};
#pragma unroll
    for (int ks = 0; ks < 8; ++ks) {
      half8 bfrag;
#pragma unroll
      for (int tt = 0; tt < 8; ++tt) {
        const float v = f2p[(ks * 32 + lk * 8 + tt) * HW];
        bfrag[tt] = (_Float16)(inb ? v : 0.0f);
      }
      acc = __builtin_amdgcn_mfma_f32_16x16x32_f16(afrag[ks], bfrag, acc, 0, 0, 0);
    }
#pragma unroll
    for (int r = 0; r < 4; ++r)
      G[(4 * lk + r) * FGP + n] = acc[r];
  }
  __syncthreads();
  float* outb = out + b * (ND * HW);
  const float invc = 1.0f / 256.0f;
  for (int o = threadIdx.x; o < ND * 16; o += 256) {
    const int d = o >> 4;
    const int m = o & 15;
    const int dy = (unsigned)d / 21u;
    const int dx = (unsigned)d % 21u;
    const int alpha = m >> 2, beta = m & 3;
    const float val = G[m * FGP + (alpha + dy) * FNJ + (beta + dx)] * invc;
    outb[d * HW + (y0 + qa + 2 * alpha) * Wn + (x0 + qb + 2 * beta)] = val;
  }
}

extern "C" void kernel_launch(void* const* d_in, const int* in_sizes, int n_in,
                              void* d_out, int out_size, void* d_ws, size_t ws_size,
                              hipStream_t stream) {
  const float* f1 = (const float*)d_in[0];
  const float* f2 = (const float*)d_in[1];
  float* out = (float*)d_out;
  if (ws_size >= WS_NEEDED) {
    _Float16* f1t = (_Float16*)d_ws;
    _Float16* f2t = (_Float16*)((char*)d_ws + F1T_BYTES);
    tconv_all<<<dim3(F1_BLKS + F2_BLKS), dim3(256), 0, stream>>>(f1, f2, f1t, f2t);
    corr6<<<dim3(Bn * 2 * NTY * NTX * 2), dim3(256), 0, stream>>>(f1t, f2t, out);
  } else {
    corr_fallback<<<dim3(Bn * FNTY * FNTX * 4), dim3(256), 0, stream>>>(f1, f2, out);
  }
}

// Round 12
// 243.197 us; speedup vs baseline: 52.2886x; 1.1836x over previous
//
#include <hip/hip_runtime.h>

typedef _Float16 half8 __attribute__((ext_vector_type(8)));
typedef float floatx4 __attribute__((ext_vector_type(4)));

constexpr int Bn = 16, Cn = 256, Hn = 64, Wn = 96;
constexpr int HW = Hn * Wn;          // 6144
constexpr int Dn = 21, ND = Dn * Dn; // 441
constexpr int PH = Hn + 40;          // 104
constexpr int PW = Wn + 40;          // 136
constexpr int PHW = PH * PW;         // 14144
constexpr int TY = 8, TX = 16;
constexpr int NTY = Hn / TY;         // 8
constexpr int NTX = Wn / TX;         // 6
constexpr int NJ = (TX + 40) / 2;    // 28 window cols per parity
constexpr int GP = 260;              // G pitch f16 (lk groups 8 banks apart)
// SMEM: stage buffer 32,768 B (512 slots x 64B) / G 2x32x260x2 = 33,280 B (union)
constexpr int SMEM_BYTES = 33280;

constexpr size_t F1T_BYTES = (size_t)Bn * HW * Cn * 2;   // 50,331,648
constexpr size_t F2T_BYTES = (size_t)Bn * PHW * Cn * 2;  // 115,867,648
constexpr size_t WS_NEEDED = F1T_BYTES + F2T_BYTES;

constexpr int F1_BLKS = Bn * (HW / 64);    // 1536
constexpr int F2_BLKS = Bn * (PHW / 64);   // 3536

// ---------------- pass 1 (merged): f32 BCHW -> f16 pixel-major ------------
__global__ __launch_bounds__(256)
void tconv_all(const float* __restrict__ f1, const float* __restrict__ f2,
               _Float16* __restrict__ f1t, _Float16* __restrict__ f2t) {
  int blk = blockIdx.x;
  const int t = threadIdx.x;
  const int pxl = t >> 2;            // 0..63
  const int g = t & 3;
  if (blk < F1_BLKS) {
    const int b = blk / (HW / 64);
    const int px = (blk % (HW / 64)) * 64 + pxl;
    const float* src = f1 + (size_t)b * Cn * HW + px;
    _Float16* dst = f1t + ((size_t)b * HW + px) * Cn;
#pragma unroll
    for (int it = 0; it < 8; ++it) {
      const int c0 = (g + it * 4) * 8;
      half8 v;
#pragma unroll
      for (int k = 0; k < 8; ++k)
        v[k] = (_Float16)src[(size_t)(c0 + k) * HW];
      *(half8*)(dst + c0) = v;
    }
  } else {
    blk -= F1_BLKS;
    const int b = blk / (PHW / 64);
    const int ppx = (blk % (PHW / 64)) * 64 + pxl;
    const int y = ppx / PW;
    const int x = ppx - y * PW;
    const int yy = y - 20, xx = x - 20;
    const bool valid = (yy >= 0) & (yy < Hn) & (xx >= 0) & (xx < Wn);
    const float* src = f2 + (size_t)b * Cn * HW + (valid ? (yy * Wn + xx) : 0);
    _Float16* dst = f2t + ((size_t)b * PHW + ppx) * Cn;
#pragma unroll
    for (int it = 0; it < 8; ++it) {
      const int c0 = (g + it * 4) * 8;
      half8 v;
#pragma unroll
      for (int k = 0; k < 8; ++k) {
        const float f = src[(size_t)(c0 + k) * HW];
        v[k] = (_Float16)(valid ? f : 0.0f);
      }
      *(half8*)(dst + c0) = v;
    }
  }
}

// ---------------- pass 2: K-outer cooperative staged MFMA -----------------
// One wg = (b, qa, 8x16 tile, dy-chunk), BOTH x-parity classes.
// Per K-slice (32 ch): all 256 threads DMA the window slice into LDS via
// global_load_lds (no dest VGPRs -> nothing for the allocator to serialize),
// barrier (vmcnt(0) drain), waves read B fragments from LDS + MFMA into
// register-resident accumulators, barrier. Epilogue reuses LDS for G.
__global__ __launch_bounds__(256, 4)
void corr7(const _Float16* __restrict__ f1t, const _Float16* __restrict__ f2t,
           float* __restrict__ out) {
  __shared__ __align__(16) char SMEM[SMEM_BYTES];

  // bijective XCD swizzle: 6144 wgs = 8 XCDs x 768 contiguous
  int bid = (int)blockIdx.x;
  bid = (bid & 7) * 768 + (bid >> 3);
  const int tx = bid % NTX;
  int tmp = bid / NTX;
  const int ty = tmp % NTY;
  tmp /= NTY;
  const int qa = tmp & 1;
  tmp >>= 1;
  const int chunk = tmp & 3;
  const int b = tmp >> 2;
  const int y0 = ty * TY, x0 = tx * TX;

  // dy chunks (6,5,5,5): dyLo 0,6,11,16; window rows = r+3
  const int r = (chunk == 0) ? 6 : 5;
  const int dyLo = (chunk == 0) ? 0 : (1 + 5 * chunk);
  const int rows = r + 3;                 // 9 / 8
  const int NNc = rows * NJ;              // 252 / 224
  const int NSLOT = 2 * NNc;              // 504 / 448 (both qb)
  const int RND = (NSLOT + 63) >> 6;      // 8 / 7 stage rounds
  const int ndch = r * Dn;                // 126 / 105

  const int t = threadIdx.x;
  const int lane = t & 63;
  const int wave = t >> 6;
  const int l15 = lane & 15;
  const int lk = lane >> 4;
  const int qb = wave >> 1;               // waves 0,1 -> qb0; 2,3 -> qb1
  const int half = wave & 1;              // tile-range half

  const _Float16* f1b = f1t + (size_t)b * HW * Cn;
  const _Float16* f2b = f2t + (size_t)b * PHW * Cn;
  const float invc = 1.0f / 256.0f;

  // ---- stage source offsets (elements), one per round, quarter-rotated.
  // slot s holds window pixel (sqb, n); lane quarter qpos stores global
  // quarter qsrc = (qpos - rot(s)) & 3 so reads can be bank-spread.
  unsigned soff[8];
#pragma unroll
  for (int rr = 0; rr < 8; ++rr) {
    int s = rr * 64 + (t >> 2);
    if (s >= NSLOT) s = 0;                // pad rounds: dup load (write to pad)
    const int sqb = (s >= NNc) ? 1 : 0;
    const int n = s - sqb * NNc;
    const int i = n / NJ;
    const int j = n - i * NJ;
    const int py = y0 + qa + 2 * (i + dyLo);
    const int px = x0 + sqb + 2 * j;
    const int rot = (s + (s >> 2)) & 3;
    const int qsrc = ((t & 3) - rot) & 3;
    soff[rr] = (unsigned)((py * PW + px) * Cn + qsrc * 8);
  }

  // wave-uniform LDS stage base (lane*16 is added by HW)
  const unsigned sbase = __builtin_amdgcn_readfirstlane((unsigned)(wave * 1024));

  // ---- per-tile LDS read byte offsets (swizzled), constant across slices
  unsigned rdoff[8];
#pragma unroll
  for (int ti = 0; ti < 8; ++ti) {
    const int tile = half * 8 + ti;
    const int n = tile * 16 + l15;
    const int s = qb * NNc + n;           // < 512 always
    const int rot = (s + (s >> 2)) & 3;
    rdoff[ti] = (unsigned)(s * 64 + ((lk + rot) & 3) * 16);
  }

  // ---- A source offsets (m-tile1 = m-tile0 + 4 rows)
  const int ay = y0 + qa + 2 * (l15 >> 3);
  const int ax = x0 + qb + 2 * (l15 & 7);
  const unsigned aoff = (unsigned)((ay * Wn + ax) * Cn + lk * 8);
  const unsigned astep = (unsigned)(4 * Wn * Cn);

  floatx4 acc0[8], acc1[8];
#pragma unroll
  for (int i = 0; i < 8; ++i) {
    acc0[i] = {0.f, 0.f, 0.f, 0.f};
    acc1[i] = {0.f, 0.f, 0.f, 0.f};
  }

  for (int ks0 = 0; ks0 < 8; ++ks0) {
    const unsigned kb = (unsigned)(ks0 * 32);
    // stage DMAs: 8 per thread, independent, zero dest VGPRs
#pragma unroll
    for (int rr = 0; rr < 8; ++rr) {
      if (rr < RND) {
        __builtin_amdgcn_global_load_lds(
            (const __attribute__((address_space(1))) void*)(f2b + soff[rr] + kb),
            (__attribute__((address_space(3))) void*)(SMEM + sbase + rr * 4096),
            16, 0, 0);
      }
    }
    // A fragments for this slice (latency overlaps the DMA drain)
    const half8 a0 = *(const half8*)(f1b + aoff + kb);
    const half8 a1 = *(const half8*)(f1b + aoff + astep + kb);
    __syncthreads();   // compiler emits s_waitcnt vmcnt(0) before s_barrier

    // 8 tiles x 2 m-tiles: B from LDS, MFMA into resident acc
#pragma unroll
    for (int ti = 0; ti < 8; ++ti) {
      const half8 bf = *(const half8*)(SMEM + rdoff[ti]);
      acc0[ti] = __builtin_amdgcn_mfma_f32_16x16x32_f16(a0, bf, acc0[ti], 0, 0, 0);
      acc1[ti] = __builtin_amdgcn_mfma_f32_16x16x32_f16(a1, bf, acc1[ti], 0, 0, 0);
    }
    __syncthreads();   // stage buffer consumed; next slice may overwrite
  }

  // ---- deposit G into LDS (reuses SMEM; stage buffer dead)
  _Float16* const Gh = (_Float16*)SMEM;   // G[qb][m][n] at (qb*32+m)*GP + n
#pragma unroll
  for (int ti = 0; ti < 8; ++ti) {
    const int tile = half * 8 + ti;
    const int n = tile * 16 + l15;
    if (n < NNc) {
#pragma unroll
      for (int rr2 = 0; rr2 < 4; ++rr2) {
        Gh[(qb * 32 + 4 * lk + rr2) * GP + n]      = (_Float16)(acc0[ti][rr2] * invc);
        Gh[(qb * 32 + 16 + 4 * lk + rr2) * GP + n] = (_Float16)(acc1[ti][rr2] * invc);
      }
    }
  }
  __syncthreads();

  // ---- merged epilogue (round-10 verified): full 64B lines
  {
    const int niter = (ndch + 15) >> 4;
    const int dsub = t >> 4;
    const int alpha = (t >> 2) & 3;
    const int xq = t & 3;
    const int yy = y0 + qa + 2 * alpha;
    float* ob = out + (size_t)b * ND * HW + yy * Wn + x0 + xq * 4;
    const int m0 = alpha * 8 + xq * 2;
    for (int q = 0; q < niter; ++q) {
      const int dch = q * 16 + dsub;
      if (dch < ndch) {
        const unsigned dyl = (unsigned)dch / 21u;
        const int dx = dch - (int)dyl * 21;
        const int dy = dyLo + (int)dyl;
        const int col = ((int)dyl + alpha) * NJ + xq * 2 + dx;
        floatx4 v;
        v[0] = (float)Gh[(0 * 32 + m0) * GP + col];
        v[1] = (float)Gh[(1 * 32 + m0) * GP + col];
        v[2] = (float)Gh[(0 * 32 + m0 + 1) * GP + col + 1];
        v[3] = (float)Gh[(1 * 32 + m0 + 1) * GP + col + 1];
        __builtin_nontemporal_store(v, (floatx4*)(ob + (size_t)(dy * Dn + dx) * HW));
      }
    }
  }
}

// ---------------- fallback (round-1 kernel) if ws too small ---------------
constexpr int FTY = 8, FTX = 8;
constexpr int FNTY = Hn / FTY, FNTX = Wn / FTX;
constexpr int FNJ = 24, FNTILES = 36, FGP = 580;

__global__ __launch_bounds__(256, 4)
void corr_fallback(const float* __restrict__ f1, const float* __restrict__ f2,
                   float* __restrict__ out) {
  __shared__ float G[16 * FGP];
  const int bid = blockIdx.x;
  const int cls = bid & 3;
  const int t2 = bid >> 2;
  const int tx = t2 % FNTX;
  const int t3 = t2 / FNTX;
  const int ty = t3 % FNTY;
  const int b = t3 / FNTY;
  const int qa = cls >> 1, qb = cls & 1;
  const int y0 = ty * FTY, x0 = tx * FTX;
  const int lane = threadIdx.x & 63;
  const int wave = threadIdx.x >> 6;
  const int l15 = lane & 15;
  const int lk = lane >> 4;
  const float* f1b = f1 + b * (Cn * HW);
  const float* f2b = f2 + b * (Cn * HW);
  const int ay = y0 + qa + 2 * (l15 >> 2);
  const int ax = x0 + qb + 2 * (l15 & 3);
  const float* f1p = f1b + ay * Wn + ax;
  half8 afrag[8];
#pragma unroll
  for (int ks = 0; ks < 8; ++ks)
#pragma unroll
    for (int tt = 0; tt < 8; ++tt)
      afrag[ks][tt] = (_Float16)f1p[(ks * 32 + lk * 8 + tt) * HW];
  const int nt0 = wave * (FNTILES / 4);
  for (int nt = nt0; nt < nt0 + FNTILES / 4; ++nt) {
    const unsigned n = nt * 16 + l15;
    const int i = n / (unsigned)FNJ;
    const int j = n % (unsigned)FNJ;
    const int y2 = y0 - 20 + qa + 2 * i;
    const int x2 = x0 - 20 + qb + 2 * j;
    const bool inb = (y2 >= 0) & (y2 < Hn) & (x2 >= 0) & (x2 < Wn);
    const float* f2p = f2b + (inb ? (y2 * Wn + x2) : 0);
    floatx4 acc = {0.f, 0.f, 0.f, 0.f};
#pragma unroll
    for (int ks = 0; ks < 8; ++ks) {
      half8 bfrag;
#pragma unroll
      for (int tt = 0; tt < 8; ++tt) {
        const float v = f2p[(ks * 32 + lk * 8 + tt) * HW];
        bfrag[tt] = (_Float16)(inb ? v : 0.0f);
      }
      acc = __builtin_amdgcn_mfma_f32_16x16x32_f16(afrag[ks], bfrag, acc, 0, 0, 0);
    }
#pragma unroll
    for (int r = 0; r < 4; ++r)
      G[(4 * lk + r) * FGP + n] = acc[r];
  }
  __syncthreads();
  float* outb = out + b * (ND * HW);
  const float invc = 1.0f / 256.0f;
  for (int o = threadIdx.x; o < ND * 16; o += 256) {
    const int d = o >> 4;
    const int m = o & 15;
    const int dy = (unsigned)d / 21u;
    const int dx = (unsigned)d % 21u;
    const int alpha = m >> 2, beta = m & 3;
    const float val = G[m * FGP + (alpha + dy) * FNJ + (beta + dx)] * invc;
    outb[d * HW + (y0 + qa + 2 * alpha) * Wn + (x0 + qb + 2 * beta)] = val;
  }
}

extern "C" void kernel_launch(void* const* d_in, const int* in_sizes, int n_in,
                              void* d_out, int out_size, void* d_ws, size_t ws_size,
                              hipStream_t stream) {
  const float* f1 = (const float*)d_in[0];
  const float* f2 = (const float*)d_in[1];
  float* out = (float*)d_out;
  if (ws_size >= WS_NEEDED) {
    _Float16* f1t = (_Float16*)d_ws;
    _Float16* f2t = (_Float16*)((char*)d_ws + F1T_BYTES);
    tconv_all<<<dim3(F1_BLKS + F2_BLKS), dim3(256), 0, stream>>>(f1, f2, f1t, f2t);
    corr7<<<dim3(Bn * 2 * NTY * NTX * 4), dim3(256), 0, stream>>>(f1t, f2t, out);
  } else {
    corr_fallback<<<dim3(Bn * FNTY * FNTX * 4), dim3(256), 0, stream>>>(f1, f2, out);
  }
}